// Round 4
// baseline (135.559 us; speedup 1.0000x reference)
//
#include <hip/hip_runtime.h>

// BlockSparseAttention B=2,H=16,N=2048,D=64 fp32, block-causal.
// R4: (1) 512-thread WGs, heavy+light q-tile pair per WG; wave-group 1 finishes
// the light tile then takes the heavy tile's K-tail (split-K; fixed-max softmax
// makes partials additive) -> exactly 18 sub-tiles per wave-group, zero tail.
// (2) prep V-transpose re-assigned wave-per-16-d so LDS scatter is 2-way (free).
// Blob image formats identical to R3 (verified correct).

typedef short bf16x8 __attribute__((ext_vector_type(8)));
typedef float f32x4  __attribute__((ext_vector_type(4)));
typedef unsigned short u16;
typedef u16 u16x8 __attribute__((ext_vector_type(8)));

#define MFMA(A,B,C) __builtin_amdgcn_mfma_f32_16x16x32_bf16((A),(B),(C),0,0,0)

__device__ __forceinline__ u16 f2bf_rne(float f) {
    union { float f; unsigned u; } c; c.f = f;
    unsigned r = c.u + 0x7FFFu + ((c.u >> 16) & 1u);
    return (u16)(r >> 16);
}
__device__ __forceinline__ u16 f2bf_fast(float f) {
    union { float f; unsigned u; } c; c.f = f;
    return (u16)((c.u + 0x8000u) >> 16);
}

// ---- prepass: per (bh,64-key tile) 16KB blob = K-image(8KB u16[4096]) + V^T-image(8KB)
// K-image: u16 idx = key*64 + ((ch + (key&3) + 4*((key>>3)&1))&7)*8 + (d&7),  ch=d>>3
// V-image: u16 idx = 4096 + d*64 + (((key>>3) + (d&7))&7)*8 + (key&7)
__global__ __launch_bounds__(256)
void prep_kernel(const float* __restrict__ K, const float* __restrict__ V,
                 u16* __restrict__ blob)
{
    int bt = blockIdx.x;                 // bh*32 + tile
    int tid = threadIdx.x;
    const size_t gbase = (size_t)bt * 4096;
    u16* bb = blob + (size_t)bt * 8192;
    __shared__ __align__(16) u16 lt[4096];

    // K path: direct to global, conflict-free
    {
        int key = tid >> 2, c2 = (tid & 3) << 1;
        int rotb = (key & 3) + 4 * ((key >> 3) & 1);
        const float* kp = K + gbase + key * 64 + c2 * 8;
        float4 x0 = *(const float4*)kp,       x1 = *(const float4*)(kp + 4);
        float4 x2 = *(const float4*)(kp + 8), x3 = *(const float4*)(kp + 12);
        u16x8 a, b;
        a[0]=f2bf_rne(x0.x); a[1]=f2bf_rne(x0.y); a[2]=f2bf_rne(x0.z); a[3]=f2bf_rne(x0.w);
        a[4]=f2bf_rne(x1.x); a[5]=f2bf_rne(x1.y); a[6]=f2bf_rne(x1.z); a[7]=f2bf_rne(x1.w);
        b[0]=f2bf_rne(x2.x); b[1]=f2bf_rne(x2.y); b[2]=f2bf_rne(x2.z); b[3]=f2bf_rne(x2.w);
        b[4]=f2bf_rne(x3.x); b[5]=f2bf_rne(x3.y); b[6]=f2bf_rne(x3.z); b[7]=f2bf_rne(x3.w);
        *(u16x8*)&bb[key * 64 + (((c2    ) + rotb) & 7) * 8] = a;
        *(u16x8*)&bb[key * 64 + (((c2 + 1) + rotb) & 7) * 8] = b;
    }
    // V path: wave w owns d in [16w,16w+16), lane = key -> 2-way LDS stores (free)
    {
        int wv = tid >> 6, ln = tid & 63;
        const float* vp = V + gbase + ln * 64 + wv * 16;
        float4 y0 = *(const float4*)vp,       y1 = *(const float4*)(vp + 4);
        float4 y2 = *(const float4*)(vp + 8), y3 = *(const float4*)(vp + 12);
        float yy[16] = { y0.x,y0.y,y0.z,y0.w, y1.x,y1.y,y1.z,y1.w,
                         y2.x,y2.y,y2.z,y2.w, y3.x,y3.y,y3.z,y3.w };
        int kc = ln >> 3, kw = ln & 7;
        #pragma unroll
        for (int j = 0; j < 16; ++j) {
            int d = wv * 16 + j;                       // d&7 == j&7
            lt[d * 64 + ((kc + (j & 7)) & 7) * 8 + kw] = f2bf_rne(yy[j]);
        }
    }
    __syncthreads();
    {
        int o = tid * 16;
        *(u16x8*)&bb[4096 + o]     = *(const u16x8*)&lt[o];
        *(u16x8*)&bb[4096 + o + 8] = *(const u16x8*)&lt[o + 8];
    }
}

// ---- main: 512 threads, 2 wave-groups ----
__global__ __launch_bounds__(512, 4)
void bsattn_main(const float* __restrict__ Q, const float* __restrict__ SC,
                 const int* __restrict__ RS, const int* __restrict__ RE,
                 const u16* __restrict__ blob, float* __restrict__ O)
{
    constexpr int N = 2048, D = 64;
    int wg = blockIdx.x;
    int bh = wg & 31, pr = wg >> 5;          // pr 0..15
    int qtA = 31 - pr, qtB = pr;             // heavy / light 64-row q-tiles
    int tid = threadIdx.x;
    int grp = tid >> 8;                      // wave-group 0/1
    int wid = (tid >> 6) & 3;
    int lane = tid & 63;
    int n = lane & 15, g = lane >> 4;

    __shared__ __align__(16) unsigned char smem[33280];
    u16*   buf0 = (u16*)smem;                // 16 KB tile image
    u16*   buf1 = (u16*)(smem + 16384);      // 16 KB tile image
    float* cmb  = (float*)smem;              // aliases buffers (post-loop only)
    float* cl   = (float*)(smem + 32768);    // 64 f32
    int*   sbi  = (int*)(smem + 33024);      // 8 waves * 4 ints

    int myqt  = grp ? qtB : qtA;
    int myrow = (myqt << 6) + wid * 16 + n;
    int rs_l = RS[myrow], re_l = RE[myrow];
    {
        int a = rs_l, b = rs_l, c = re_l, d = re_l;
        #pragma unroll
        for (int o = 1; o < 16; o <<= 1) {
            a = min(a, __shfl_xor(a, o)); b = max(b, __shfl_xor(b, o));
            c = min(c, __shfl_xor(c, o)); d = max(d, __shfl_xor(d, o));
        }
        if (lane == 0) {
            int* p = &sbi[(grp * 4 + wid) * 4];
            p[0] = a; p[1] = b; p[2] = c; p[3] = d;
        }
    }
    float sscale = SC[0] * 1.44269504088896340736f;   // exp2 domain

    bf16x8 qf0, qf1;
    auto loadQ = [&](int row) {
        const float* qp = Q + ((size_t)bh * N + row) * D + g * 8;
        float4 a0 = *(const float4*)qp,        a1 = *(const float4*)(qp + 4);
        float4 b0 = *(const float4*)(qp + 32), b1 = *(const float4*)(qp + 36);
        qf0[0]=f2bf_rne(a0.x*sscale); qf0[1]=f2bf_rne(a0.y*sscale);
        qf0[2]=f2bf_rne(a0.z*sscale); qf0[3]=f2bf_rne(a0.w*sscale);
        qf0[4]=f2bf_rne(a1.x*sscale); qf0[5]=f2bf_rne(a1.y*sscale);
        qf0[6]=f2bf_rne(a1.z*sscale); qf0[7]=f2bf_rne(a1.w*sscale);
        qf1[0]=f2bf_rne(b0.x*sscale); qf1[1]=f2bf_rne(b0.y*sscale);
        qf1[2]=f2bf_rne(b0.z*sscale); qf1[3]=f2bf_rne(b0.w*sscale);
        qf1[4]=f2bf_rne(b1.x*sscale); qf1[5]=f2bf_rne(b1.y*sscale);
        qf1[6]=f2bf_rne(b1.z*sscale); qf1[7]=f2bf_rne(b1.w*sscale);
    };
    loadQ(myrow);

    __syncthreads();
    int rsminA = min(min(sbi[0],  sbi[4]),  min(sbi[8],  sbi[12]));
    int rsmaxA = max(max(sbi[1],  sbi[5]),  max(sbi[9],  sbi[13]));
    int reminA = min(min(sbi[2],  sbi[6]),  min(sbi[10], sbi[14]));
    int remaxA = max(max(sbi[3],  sbi[7]),  max(sbi[11], sbi[15]));
    int rsminB = min(min(sbi[16], sbi[20]), min(sbi[24], sbi[28]));
    int rsmaxB = max(max(sbi[17], sbi[21]), max(sbi[25], sbi[29]));
    int reminB = min(min(sbi[18], sbi[22]), min(sbi[26], sbi[30]));
    int remaxB = max(max(sbi[19], sbi[23]), max(sbi[27], sbi[31]));

    int sA = rsminA >> 6;
    int wA = (remaxA - (sA << 6) + 63) >> 6;
    int sB = rsminB >> 6;
    int wB = (remaxB - (sB << 6) + 63) >> 6;
    int n0 = (wA + wB + 1) >> 1; if (n0 > wA) n0 = wA;   // grp0: qtA tiles [0,n0)
    int c1 = wB + wA - n0;                               // grp1 count
    int M  = max(n0, c1);

    int mk_rsmax = grp ? rsmaxB : rsmaxA;
    int mk_remin = grp ? reminB : reminA;

    f32x4 acc[4], accl = {0.f, 0.f, 0.f, 0.f};
    #pragma unroll
    for (int c = 0; c < 4; ++c) acc[c] = (f32x4){0.f, 0.f, 0.f, 0.f};
    bf16x8 ones;
    #pragma unroll
    for (int j = 0; j < 8; ++j) ones[j] = (short)0x3F80;

    // loop-invariant LDS read offsets (u16 indices; same images as R3)
    int rA   = ((n >> 2) << 3) + (n & 3);
    int phk  = (n & 3) + 4 * ((n >> 2) & 1);
    int osA0 = rA * 64 + ((g + phk) & 7) * 8;
    int osA1 = rA * 64 + ((g + 4 + phk) & 7) * 8;
    int ov0  = 4096 + n * 64 + ((    g + (n & 7)) & 7) * 8;
    int ov1  = 4096 + n * 64 + ((4 + g + (n & 7)) & 7) * 8;

    auto proc = [&](int kb, const u16* ls) {
        float sc[16];
        #pragma unroll
        for (int h = 0; h < 2; ++h) {
            int hb = h * 2048;
            f32x4 t0 = {0.f,0.f,0.f,0.f}, t1 = t0;
            t0 = MFMA(*(const bf16x8*)&ls[hb + osA0],       qf0, t0);
            t0 = MFMA(*(const bf16x8*)&ls[hb + osA1],       qf1, t0);
            t1 = MFMA(*(const bf16x8*)&ls[hb + osA0 + 256], qf0, t1);
            t1 = MFMA(*(const bf16x8*)&ls[hb + osA1 + 256], qf1, t1);
            #pragma unroll
            for (int r = 0; r < 4; ++r) { sc[h*8 + r] = t0[r]; sc[h*8 + 4 + r] = t1[r]; }
        }
        if (kb < mk_rsmax || kb + 64 > mk_remin) {
            #pragma unroll
            for (int h = 0; h < 2; ++h)
                #pragma unroll
                for (int j = 0; j < 8; ++j) {
                    int key = kb + h * 32 + g * 8 + j;
                    if (key < rs_l || key >= re_l) sc[h*8 + j] = -1e30f;
                }
        }
        bf16x8 pf0, pf1;
        #pragma unroll
        for (int j = 0; j < 8; ++j) { float p = __builtin_amdgcn_exp2f(sc[j]);     pf0[j] = (short)f2bf_fast(p); }
        #pragma unroll
        for (int j = 0; j < 8; ++j) { float p = __builtin_amdgcn_exp2f(sc[8 + j]); pf1[j] = (short)f2bf_fast(p); }
        #pragma unroll
        for (int h = 0; h < 2; ++h) {
            const bf16x8& pf = h ? pf1 : pf0;
            int ov = h ? ov1 : ov0;
            acc[0] = MFMA(pf, *(const bf16x8*)&ls[ov       ], acc[0]);
            acc[1] = MFMA(pf, *(const bf16x8*)&ls[ov + 1024], acc[1]);
            acc[2] = MFMA(pf, *(const bf16x8*)&ls[ov + 2048], acc[2]);
            acc[3] = MFMA(pf, *(const bf16x8*)&ls[ov + 3072], acc[3]);
            accl   = MFMA(pf, ones, accl);
        }
    };

    auto epilogue = [&](int qt) {
        int rb = g << 2;
        int orow = (qt << 6) + wid * 16 + rb;
        float* ob = O + ((size_t)bh * N + orow) * D + n;
        #pragma unroll
        for (int r = 0; r < 4; ++r) {
            float li = 1.0f / accl[r];
            float* rp = ob + (size_t)r * D;
            rp[0]  = acc[0][r] * li;
            rp[16] = acc[1][r] * li;
            rp[32] = acc[2][r] * li;
            rp[48] = acc[3][r] * li;
        }
    };

    bool onB = (grp == 1);
    for (int i = 0; i < M; ++i) {
        int  tA = sA + i;
        bool v0 = (i < n0);
        int  j  = i - wB;
        bool v1 = (i < wB) || (j < wA - n0);
        int  tBt = (i < wB) ? (sB + i) : (sA + n0 + j);
        bool sh = v0 && v1 && (tBt == tA);
        __syncthreads();
        if (grp == 0) {
            if (v0) {
                const u16* src = blob + (size_t)(bh * 32 + tA) * 8192;
                int o = (tid & 255) * 32;
                #pragma unroll
                for (int q8 = 0; q8 < 4; ++q8)
                    *(u16x8*)&buf0[o + q8 * 8] = *(const u16x8*)&src[o + q8 * 8];
            }
        } else {
            if (v1 && !sh) {
                const u16* src = blob + (size_t)(bh * 32 + tBt) * 8192;
                int o = (tid & 255) * 32;
                #pragma unroll
                for (int q8 = 0; q8 < 4; ++q8)
                    *(u16x8*)&buf1[o + q8 * 8] = *(const u16x8*)&src[o + q8 * 8];
            }
        }
        __syncthreads();
        if (grp == 0) {
            if (v0) proc(tA << 6, buf0);
        } else {
            if (onB && i == wB) {                 // finished light tile: flush, switch to A-tail
                if (wB > 0) epilogue(qtB);
                myrow = (qtA << 6) + wid * 16 + n;
                rs_l = RS[myrow]; re_l = RE[myrow];
                mk_rsmax = rsmaxA; mk_remin = reminA;
                loadQ(myrow);
                #pragma unroll
                for (int c = 0; c < 4; ++c) acc[c] = (f32x4){0.f, 0.f, 0.f, 0.f};
                accl = (f32x4){0.f, 0.f, 0.f, 0.f};
                onB = false;
            }
            if (v1) proc(tBt << 6, sh ? buf0 : buf1);
        }
    }

    __syncthreads();
    if (grp == 1) {
        if (onB) {                                // loop ended while still on B (general case)
            if (wB > 0) epilogue(qtB);
            #pragma unroll
            for (int c = 0; c < 4; ++c) acc[c] = (f32x4){0.f, 0.f, 0.f, 0.f};
            accl = (f32x4){0.f, 0.f, 0.f, 0.f};
        }
        // write qtA split-K partial (2-way-banked layout)
        #pragma unroll
        for (int c = 0; c < 4; ++c)
            #pragma unroll
            for (int r = 0; r < 4; ++r)
                cmb[(wid * 16 + g * 4 + r) * 64 + ((c * 16 + n) ^ (g * 8))] = acc[c][r];
        if (n == 0) {
            #pragma unroll
            for (int r = 0; r < 4; ++r) cl[wid * 16 + g * 4 + r] = accl[r];
        }
    }
    __syncthreads();
    if (grp == 0) {
        #pragma unroll
        for (int c = 0; c < 4; ++c)
            #pragma unroll
            for (int r = 0; r < 4; ++r)
                acc[c][r] += cmb[(wid * 16 + g * 4 + r) * 64 + ((c * 16 + n) ^ (g * 8))];
        #pragma unroll
        for (int r = 0; r < 4; ++r) accl[r] += cl[wid * 16 + g * 4 + r];
        epilogue(qtA);
    }
}

extern "C" void kernel_launch(void* const* d_in, const int* in_sizes, int n_in,
                              void* d_out, int out_size, void* d_ws, size_t ws_size,
                              hipStream_t stream) {
    const float* q  = (const float*)d_in[0];
    const float* k  = (const float*)d_in[1];
    const float* v  = (const float*)d_in[2];
    const float* sc = (const float*)d_in[3];
    const int* rs   = (const int*)d_in[4];
    const int* re   = (const int*)d_in[5];
    float* out      = (float*)d_out;
    u16* blob       = (u16*)d_ws;   // 32 bh * 32 tiles * 16KB = 16.8 MB

    prep_kernel<<<dim3(1024), dim3(256), 0, stream>>>(k, v, blob);
    bsattn_main<<<dim3(512), dim3(512), 0, stream>>>(q, sc, rs, re, blob, out);
}

// Round 5
// 131.376 us; speedup vs baseline: 1.0318x; 1.0318x over previous
//
#include <hip/hip_runtime.h>

// BlockSparseAttention B=2,H=16,N=2048,D=64 fp32, block-causal.
// R5: 256-thread WGs (4/CU resident), async double-buffered tile staging via
// global_load_lds width=16 (DMA, no VGPR roundtrip, conflict-free, 1 barrier/iter,
// prefetch overlaps compute), static per-CU-balanced q-tile schedule.
// Blob images identical to R3/R4 (verified).

typedef short bf16x8 __attribute__((ext_vector_type(8)));
typedef float f32x4  __attribute__((ext_vector_type(4)));
typedef unsigned short u16;
typedef u16 u16x8 __attribute__((ext_vector_type(8)));

#define MFMA(A,B,C) __builtin_amdgcn_mfma_f32_16x16x32_bf16((A),(B),(C),0,0,0)

__device__ __forceinline__ u16 f2bf_rne(float f) {
    union { float f; unsigned u; } c; c.f = f;
    unsigned r = c.u + 0x7FFFu + ((c.u >> 16) & 1u);
    return (u16)(r >> 16);
}
__device__ __forceinline__ u16 f2bf_fast(float f) {
    union { float f; unsigned u; } c; c.f = f;
    return (u16)((c.u + 0x8000u) >> 16);
}

// async DMA: 16 B per lane, lands at wave-uniform lds base + lane*16
__device__ __forceinline__ void gload_lds16(const void* g, void* lds) {
    __builtin_amdgcn_global_load_lds(
        (const __attribute__((address_space(1))) unsigned int*)g,
        (__attribute__((address_space(3))) unsigned int*)lds, 16, 0, 0);
}

// ---- prepass (unchanged from R4): per (bh,64-key tile) 16KB blob ----
// K-image: u16 idx = key*64 + ((ch + (key&3) + 4*((key>>3)&1))&7)*8 + (d&7), ch=d>>3
// V-image: u16 idx = 4096 + d*64 + (((key>>3) + (d&7))&7)*8 + (key&7)
__global__ __launch_bounds__(256)
void prep_kernel(const float* __restrict__ K, const float* __restrict__ V,
                 u16* __restrict__ blob)
{
    int bt = blockIdx.x;
    int tid = threadIdx.x;
    const size_t gbase = (size_t)bt * 4096;
    u16* bb = blob + (size_t)bt * 8192;
    __shared__ __align__(16) u16 lt[4096];
    {
        int key = tid >> 2, c2 = (tid & 3) << 1;
        int rotb = (key & 3) + 4 * ((key >> 3) & 1);
        const float* kp = K + gbase + key * 64 + c2 * 8;
        float4 x0 = *(const float4*)kp,       x1 = *(const float4*)(kp + 4);
        float4 x2 = *(const float4*)(kp + 8), x3 = *(const float4*)(kp + 12);
        u16x8 a, b;
        a[0]=f2bf_rne(x0.x); a[1]=f2bf_rne(x0.y); a[2]=f2bf_rne(x0.z); a[3]=f2bf_rne(x0.w);
        a[4]=f2bf_rne(x1.x); a[5]=f2bf_rne(x1.y); a[6]=f2bf_rne(x1.z); a[7]=f2bf_rne(x1.w);
        b[0]=f2bf_rne(x2.x); b[1]=f2bf_rne(x2.y); b[2]=f2bf_rne(x2.z); b[3]=f2bf_rne(x2.w);
        b[4]=f2bf_rne(x3.x); b[5]=f2bf_rne(x3.y); b[6]=f2bf_rne(x3.z); b[7]=f2bf_rne(x3.w);
        *(u16x8*)&bb[key * 64 + (((c2    ) + rotb) & 7) * 8] = a;
        *(u16x8*)&bb[key * 64 + (((c2 + 1) + rotb) & 7) * 8] = b;
    }
    {
        int wv = tid >> 6, ln = tid & 63;
        const float* vp = V + gbase + ln * 64 + wv * 16;
        float4 y0 = *(const float4*)vp,       y1 = *(const float4*)(vp + 4);
        float4 y2 = *(const float4*)(vp + 8), y3 = *(const float4*)(vp + 12);
        float yy[16] = { y0.x,y0.y,y0.z,y0.w, y1.x,y1.y,y1.z,y1.w,
                         y2.x,y2.y,y2.z,y2.w, y3.x,y3.y,y3.z,y3.w };
        int kc = ln >> 3, kw = ln & 7;
        #pragma unroll
        for (int j = 0; j < 16; ++j) {
            int d = wv * 16 + j;
            lt[d * 64 + ((kc + (j & 7)) & 7) * 8 + kw] = f2bf_rne(yy[j]);
        }
    }
    __syncthreads();
    {
        int o = tid * 16;
        *(u16x8*)&bb[4096 + o]     = *(const u16x8*)&lt[o];
        *(u16x8*)&bb[4096 + o + 8] = *(const u16x8*)&lt[o + 8];
    }
}

// ---- main ----
__global__ __launch_bounds__(256, 4)
void bsattn_main(const float* __restrict__ Q, const float* __restrict__ SC,
                 const int* __restrict__ RS, const int* __restrict__ RE,
                 const u16* __restrict__ blob, float* __restrict__ O)
{
    constexpr int N = 2048, D = 64;
    int wg = blockIdx.x;
    int bh = wg & 31;
    // static schedule: CU c's 4 resident WGs (wg = c + 256m) sum to 72 sub-tiles
    int i0 = wg >> 5, kk = i0 & 7, rr = i0 >> 3;
    int qt = (rr == 0) ? ((kk < 4) ? 28 + kk : 20 + kk)
           : (rr == 1) ? ((kk < 4) ? 20 + kk : 12 + kk)
           : (rr == 2) ? (8 + kk) : kk;
    int q0 = qt << 6;

    int tid = threadIdx.x, wid = tid >> 6, lane = tid & 63;
    int n = lane & 15, g = lane >> 4;

    __shared__ __align__(16) u16 lsm[16384];   // 2 x 16KB tile buffers
    __shared__ int sbi[16];

    int myrow = q0 + wid * 16 + n;
    int rs_l = RS[myrow], re_l = RE[myrow];
    int w_rs_min = rs_l, w_rs_max = rs_l, w_re_min = re_l, w_re_max = re_l;
    #pragma unroll
    for (int o = 1; o < 16; o <<= 1) {
        w_rs_min = min(w_rs_min, __shfl_xor(w_rs_min, o));
        w_rs_max = max(w_rs_max, __shfl_xor(w_rs_max, o));
        w_re_min = min(w_re_min, __shfl_xor(w_re_min, o));
        w_re_max = max(w_re_max, __shfl_xor(w_re_max, o));
    }
    if (lane == 0) { sbi[wid * 2] = w_rs_min; sbi[wid * 2 + 1] = w_re_max; }

    float sscale = SC[0] * 1.44269504088896340736f;   // exp2 domain

    bf16x8 qf0, qf1;
    {
        const float* qp = Q + ((size_t)bh * N + myrow) * D + g * 8;
        float4 a0 = *(const float4*)qp,        a1 = *(const float4*)(qp + 4);
        float4 b0 = *(const float4*)(qp + 32), b1 = *(const float4*)(qp + 36);
        qf0[0]=f2bf_rne(a0.x*sscale); qf0[1]=f2bf_rne(a0.y*sscale);
        qf0[2]=f2bf_rne(a0.z*sscale); qf0[3]=f2bf_rne(a0.w*sscale);
        qf0[4]=f2bf_rne(a1.x*sscale); qf0[5]=f2bf_rne(a1.y*sscale);
        qf0[6]=f2bf_rne(a1.z*sscale); qf0[7]=f2bf_rne(a1.w*sscale);
        qf1[0]=f2bf_rne(b0.x*sscale); qf1[1]=f2bf_rne(b0.y*sscale);
        qf1[2]=f2bf_rne(b0.z*sscale); qf1[3]=f2bf_rne(b0.w*sscale);
        qf1[4]=f2bf_rne(b1.x*sscale); qf1[5]=f2bf_rne(b1.y*sscale);
        qf1[6]=f2bf_rne(b1.z*sscale); qf1[7]=f2bf_rne(b1.w*sscale);
    }

    __syncthreads();
    int kst  = min(min(sbi[0], sbi[2]), min(sbi[4], sbi[6])) & ~63;
    int kend = max(max(sbi[1], sbi[3]), max(sbi[5], sbi[7]));
    int t0 = kst >> 6;
    int w  = (kend - kst + 63) >> 6;

    // loop-invariant LDS read offsets (u16 indices; R3-verified images)
    int rA   = ((n >> 2) << 3) + (n & 3);
    int phk  = (n & 3) + 4 * ((n >> 2) & 1);
    int osA0 = rA * 64 + ((g + phk) & 7) * 8;
    int osA1 = rA * 64 + ((g + 4 + phk) & 7) * 8;
    int ov0  = 4096 + n * 64 + ((    g + (n & 7)) & 7) * 8;
    int ov1  = 4096 + n * 64 + ((4 + g + (n & 7)) & 7) * 8;

    f32x4 acc[4], accl = {0.f, 0.f, 0.f, 0.f};
    #pragma unroll
    for (int c = 0; c < 4; ++c) acc[c] = (f32x4){0.f, 0.f, 0.f, 0.f};
    bf16x8 ones;
    #pragma unroll
    for (int j = 0; j < 8; ++j) ones[j] = (short)0x3F80;

    auto stage = [&](int i) {               // async DMA of tile t0+i into buf[i&1]
        if (i < w) {
            const u16* src = blob + (size_t)(bh * 32 + t0 + i) * 8192;
            u16* dst = &lsm[(i & 1) << 13];
            int wb = wid * 2048;             // wave-uniform
            #pragma unroll
            for (int c = 0; c < 4; ++c)
                gload_lds16(src + wb + c * 512 + lane * 8, dst + wb + c * 512);
        }
    };

    auto proc = [&](int kb, const u16* ls) {
        float sc[16];
        #pragma unroll
        for (int h = 0; h < 2; ++h) {
            int hb = h * 2048;
            f32x4 t0v = {0.f,0.f,0.f,0.f}, t1v = t0v;
            t0v = MFMA(*(const bf16x8*)&ls[hb + osA0],       qf0, t0v);
            t0v = MFMA(*(const bf16x8*)&ls[hb + osA1],       qf1, t0v);
            t1v = MFMA(*(const bf16x8*)&ls[hb + osA0 + 256], qf0, t1v);
            t1v = MFMA(*(const bf16x8*)&ls[hb + osA1 + 256], qf1, t1v);
            #pragma unroll
            for (int r = 0; r < 4; ++r) { sc[h*8 + r] = t0v[r]; sc[h*8 + 4 + r] = t1v[r]; }
        }
        if (kb < w_rs_max || kb + 64 > w_re_min) {      // boundary tiles only
            #pragma unroll
            for (int h = 0; h < 2; ++h)
                #pragma unroll
                for (int j = 0; j < 8; ++j) {
                    int key = kb + h * 32 + g * 8 + j;
                    if (key < rs_l || key >= re_l) sc[h*8 + j] = -1e30f;
                }
        }
        bf16x8 pf0, pf1;
        #pragma unroll
        for (int j = 0; j < 8; ++j) { float p = __builtin_amdgcn_exp2f(sc[j]);     pf0[j] = (short)f2bf_fast(p); }
        #pragma unroll
        for (int j = 0; j < 8; ++j) { float p = __builtin_amdgcn_exp2f(sc[8 + j]); pf1[j] = (short)f2bf_fast(p); }
        #pragma unroll
        for (int h = 0; h < 2; ++h) {
            const bf16x8& pf = h ? pf1 : pf0;
            int ov = h ? ov1 : ov0;
            acc[0] = MFMA(pf, *(const bf16x8*)&ls[ov       ], acc[0]);
            acc[1] = MFMA(pf, *(const bf16x8*)&ls[ov + 1024], acc[1]);
            acc[2] = MFMA(pf, *(const bf16x8*)&ls[ov + 2048], acc[2]);
            acc[3] = MFMA(pf, *(const bf16x8*)&ls[ov + 3072], acc[3]);
            accl   = MFMA(pf, ones, accl);
        }
    };

    stage(0);
    for (int i = 0; i < w; ++i) {
        __syncthreads();          // drains vmcnt: buf[i&1] ready; buf[(i+1)&1] free
        stage(i + 1);             // prefetch overlaps proc below
        proc(kst + (i << 6), &lsm[(i & 1) << 13]);
    }

    // epilogue: O[q0+wid*16+4g+r][16c+n] = acc[c][r] / accl[r]
    int rb = g << 2;
    int orow = q0 + wid * 16 + rb;
    float* ob = O + ((size_t)bh * N + orow) * D + n;
    #pragma unroll
    for (int r = 0; r < 4; ++r) {
        float li = 1.0f / accl[r];
        float* rp = ob + (size_t)r * D;
        rp[0]  = acc[0][r] * li;
        rp[16] = acc[1][r] * li;
        rp[32] = acc[2][r] * li;
        rp[48] = acc[3][r] * li;
    }
}

extern "C" void kernel_launch(void* const* d_in, const int* in_sizes, int n_in,
                              void* d_out, int out_size, void* d_ws, size_t ws_size,
                              hipStream_t stream) {
    const float* q  = (const float*)d_in[0];
    const float* k  = (const float*)d_in[1];
    const float* v  = (const float*)d_in[2];
    const float* sc = (const float*)d_in[3];
    const int* rs   = (const int*)d_in[4];
    const int* re   = (const int*)d_in[5];
    float* out      = (float*)d_out;
    u16* blob       = (u16*)d_ws;   // 32 bh * 32 tiles * 16KB = 16.8 MB

    prep_kernel<<<dim3(1024), dim3(256), 0, stream>>>(k, v, blob);
    bsattn_main<<<dim3(1024), dim3(256), 0, stream>>>(q, sc, rs, re, blob, out);
}